// Round 1
// baseline (174.850 us; speedup 1.0000x reference)
//
#include <hip/hip_runtime.h>
#include <stdint.h>

// ---------- types ----------
typedef __attribute__((ext_vector_type(8))) __bf16 fragAB;  // 8 bf16 = 4 VGPR
typedef __attribute__((ext_vector_type(4))) float f32x4;

__device__ __forceinline__ unsigned short f2bf(float f) {
    union { float f; unsigned int u; } v; v.f = f;
    unsigned int u = v.u + 0x7fffu + ((v.u >> 16) & 1u);   // RNE
    return (unsigned short)(u >> 16);
}

__device__ __forceinline__ f32x4 MFMA(fragAB a, fragAB b, f32x4 c) {
    return __builtin_amdgcn_mfma_f32_16x16x32_bf16(a, b, c, 0, 0, 0);
}

// ---------- fp32 -> bf16 convert ----------
__global__ __launch_bounds__(256) void cvt_bf16(const float* __restrict__ src,
                                                unsigned short* __restrict__ dst, int n) {
    int i = (blockIdx.x * 256 + threadIdx.x) * 4;
    if (i >= n) return;
    float4 f = *(const float4*)(src + i);
    ushort4 o;
    o.x = f2bf(f.x); o.y = f2bf(f.y); o.z = f2bf(f.z); o.w = f2bf(f.w);
    *(ushort4*)(dst + i) = o;
}

// ---------- GEMM: C(4096x1024) = A(4096x1024) * W(1024x1024,(out,in))^T + bias ----------
// mode 0: bf16 row-major out; mode 1: bf16 transposed-V out Vt[b][n][s]; mode 2: fp32 out
#define LDT 72   // LDS row stride (elems): 144B = 9*16B, breaks power-of-2 banks

__global__ __launch_bounds__(256, 2)
void gemm_bt(const unsigned short* __restrict__ A,
             const unsigned short* __restrict__ W,
             const float* __restrict__ bias,
             void* __restrict__ out, int mode)
{
    __shared__ unsigned short As[128 * LDT];
    __shared__ unsigned short Ws[128 * LDT];

    const int t = threadIdx.x;
    const int lane = t & 63;
    const int g = lane >> 4;
    const int c = lane & 15;
    const int w = t >> 6;
    const int wm = (w >> 1) * 64;
    const int wn = (w & 1) * 64;
    const int m0 = blockIdx.y * 128;
    const int n0 = blockIdx.x * 128;

    const f32x4 z = {0.f, 0.f, 0.f, 0.f};
    f32x4 acc[4][4];
#pragma unroll
    for (int mi = 0; mi < 4; ++mi)
#pragma unroll
        for (int ni = 0; ni < 4; ++ni) acc[mi][ni] = z;

    for (int kt = 0; kt < 16; ++kt) {
        const int k0 = kt * 64;
#pragma unroll
        for (int r = 0; r < 4; ++r) {                 // stage 128x64 bf16 for A and W
            const int i = t + 256 * r;
            const int row = i >> 3;
            const int c8 = (i & 7) * 8;
            const uint4 va = *(const uint4*)(A + (size_t)(m0 + row) * 1024 + k0 + c8);
            *(uint4*)(&As[row * LDT + c8]) = va;
            const uint4 vw = *(const uint4*)(W + (size_t)(n0 + row) * 1024 + k0 + c8);
            *(uint4*)(&Ws[row * LDT + c8]) = vw;
        }
        __syncthreads();
#pragma unroll
        for (int kk = 0; kk < 2; ++kk) {
            fragAB af[4], bfr[4];
#pragma unroll
            for (int mi = 0; mi < 4; ++mi)
                af[mi] = *(const fragAB*)(&As[(wm + mi * 16 + c) * LDT + kk * 32 + g * 8]);
#pragma unroll
            for (int ni = 0; ni < 4; ++ni)
                bfr[ni] = *(const fragAB*)(&Ws[(wn + ni * 16 + c) * LDT + kk * 32 + g * 8]);
#pragma unroll
            for (int mi = 0; mi < 4; ++mi)
#pragma unroll
                for (int ni = 0; ni < 4; ++ni)
                    acc[mi][ni] = MFMA(af[mi], bfr[ni], acc[mi][ni]);
        }
        __syncthreads();
    }

    float bv[4];
#pragma unroll
    for (int ni = 0; ni < 4; ++ni) bv[ni] = bias[n0 + wn + ni * 16 + c];

    if (mode == 0) {
        unsigned short* C = (unsigned short*)out;
#pragma unroll
        for (int mi = 0; mi < 4; ++mi)
#pragma unroll
            for (int ni = 0; ni < 4; ++ni)
#pragma unroll
                for (int j = 0; j < 4; ++j) {
                    const int grow = m0 + wm + mi * 16 + g * 4 + j;
                    const int gcol = n0 + wn + ni * 16 + c;
                    C[(size_t)grow * 1024 + gcol] = f2bf(acc[mi][ni][j] + bv[ni]);
                }
    } else if (mode == 1) {
        // Vt[b][n][s], n = d_model col, s = seq pos within b. C-frag j's are s-consecutive.
        unsigned short* Vt = (unsigned short*)out;
#pragma unroll
        for (int mi = 0; mi < 4; ++mi)
#pragma unroll
            for (int ni = 0; ni < 4; ++ni) {
                const int gcol = n0 + wn + ni * 16 + c;
                const int mrow = m0 + wm + mi * 16 + g * 4;
                const int bb = mrow >> 11;
                const int s = mrow & 2047;
                ushort4 pk;
                pk.x = f2bf(acc[mi][ni][0] + bv[ni]);
                pk.y = f2bf(acc[mi][ni][1] + bv[ni]);
                pk.z = f2bf(acc[mi][ni][2] + bv[ni]);
                pk.w = f2bf(acc[mi][ni][3] + bv[ni]);
                *(ushort4*)(Vt + ((size_t)bb * 1024 + gcol) * 2048 + s) = pk;
            }
    } else {
        float* C = (float*)out;
#pragma unroll
        for (int mi = 0; mi < 4; ++mi)
#pragma unroll
            for (int ni = 0; ni < 4; ++ni)
#pragma unroll
                for (int j = 0; j < 4; ++j) {
                    const int grow = m0 + wm + mi * 16 + g * 4 + j;
                    const int gcol = n0 + wn + ni * 16 + c;
                    C[(size_t)grow * 1024 + gcol] = acc[mi][ni][j] + bv[ni];
                }
    }
}

// ---------- fused sine attention ----------
// grid (16 qblocks, 16 heads, 2 batch), 256 thr. Per chunk: St = K*Q^T (C-layout regs are
// k-consecutive), P = sin(3.75*St) -> LDS P[q][k]; O += P*V via Vt (d-major, k-contig).
#define SWZ(byteoff, row) ((byteoff) ^ (((row) & 7) << 4))

__global__ __launch_bounds__(256, 2)
void attn_kernel(const unsigned short* __restrict__ Qg,
                 const unsigned short* __restrict__ Kg,
                 const unsigned short* __restrict__ Vg,   // Vt[b][n][s]
                 unsigned short* __restrict__ AO)
{
    __shared__ unsigned short Qs[128 * 64];   // [q][d]   16KB, swizzled
    __shared__ unsigned short Ks[128 * 64];   // [k][d]   16KB, swizzled
    __shared__ unsigned short Vs[64 * 128];   // [d][k]   16KB, swizzled
    __shared__ unsigned short Ps[128 * 128];  // [q][k]   32KB, swizzled

    const int t = threadIdx.x;
    const int lane = t & 63;
    const int g = lane >> 4;
    const int c = lane & 15;
    const int w = t >> 6;
    const int qb = blockIdx.x;
    const int h = blockIdx.y;
    const int b = blockIdx.z;
    const int qbase = qb * 128;

    char* const Qsb = (char*)Qs;
    char* const Ksb = (char*)Ks;
    char* const Vsb = (char*)Vs;
    char* const Psb = (char*)Ps;

#pragma unroll
    for (int r = 0; r < 4; ++r) {            // stage Q once: 128 rows x 64 bf16
        const int i = t + 256 * r;
        const int row = i >> 3;
        const int ch = i & 7;
        const uint4 v = *(const uint4*)(Qg + (size_t)(b * 2048 + qbase + row) * 1024 + h * 64 + ch * 8);
        *(uint4*)(Qsb + SWZ(row * 128 + ch * 16, row)) = v;
    }

    const f32x4 z = {0.f, 0.f, 0.f, 0.f};
    f32x4 o[2][4];
#pragma unroll
    for (int mi = 0; mi < 2; ++mi)
#pragma unroll
        for (int ni = 0; ni < 4; ++ni) o[mi][ni] = z;

    for (int kb = 0; kb < 16; ++kb) {
        __syncthreads();                     // prev PV done before overwriting K/V
#pragma unroll
        for (int r = 0; r < 4; ++r) {        // stage K chunk: 128 x 64
            const int i = t + 256 * r;
            const int row = i >> 3;
            const int ch = i & 7;
            const uint4 v = *(const uint4*)(Kg + (size_t)(b * 2048 + kb * 128 + row) * 1024 + h * 64 + ch * 8);
            *(uint4*)(Ksb + SWZ(row * 128 + ch * 16, row)) = v;
        }
#pragma unroll
        for (int r = 0; r < 4; ++r) {        // stage V chunk (transposed source): 64 x 128
            const int i = t + 256 * r;
            const int dd = i >> 4;
            const int ch = i & 15;
            const uint4 v = *(const uint4*)(Vg + ((size_t)b * 1024 + h * 64 + dd) * 2048 + kb * 128 + ch * 8);
            *(uint4*)(Vsb + SWZ(dd * 256 + ch * 16, dd)) = v;
        }
        __syncthreads();

        // St = K*Q^T: wave w owns k rows [32w, 32w+32), all 128 q cols
        f32x4 st[2][8];
#pragma unroll
        for (int ki = 0; ki < 2; ++ki)
#pragma unroll
            for (int qi = 0; qi < 8; ++qi) st[ki][qi] = z;

#pragma unroll
        for (int kk = 0; kk < 2; ++kk) {
            fragAB kf[2], qf[8];
#pragma unroll
            for (int ki = 0; ki < 2; ++ki) {
                const int row = w * 32 + ki * 16 + c;
                kf[ki] = *(const fragAB*)(Ksb + SWZ(row * 128 + kk * 64 + g * 16, row));
            }
#pragma unroll
            for (int qi = 0; qi < 8; ++qi) {
                const int q = qi * 16 + c;
                qf[qi] = *(const fragAB*)(Qsb + SWZ(q * 128 + kk * 64 + g * 16, q));
            }
#pragma unroll
            for (int ki = 0; ki < 2; ++ki)
#pragma unroll
                for (int qi = 0; qi < 8; ++qi)
                    st[ki][qi] = MFMA(kf[ki], qf[qi], st[ki][qi]);
        }

        // P = sin(30/8 * St), write P[q][k] (C-layout regs j are k-consecutive -> 8B stores)
#pragma unroll
        for (int ki = 0; ki < 2; ++ki)
#pragma unroll
            for (int qi = 0; qi < 8; ++qi) {
                const int q = qi * 16 + c;
                ushort4 pk;
                pk.x = f2bf(__sinf(3.75f * st[ki][qi][0]));
                pk.y = f2bf(__sinf(3.75f * st[ki][qi][1]));
                pk.z = f2bf(__sinf(3.75f * st[ki][qi][2]));
                pk.w = f2bf(__sinf(3.75f * st[ki][qi][3]));
                const int kbyte = (w * 32 + ki * 16 + g * 4) * 2;
                *(ushort4*)(Psb + SWZ(q * 256 + kbyte, q)) = pk;
            }
        __syncthreads();

        // O += P * V: wave w owns q rows [32w, 32w+32), d = 0..63
#pragma unroll
        for (int kk = 0; kk < 4; ++kk) {
            fragAB pf[2], vf[4];
#pragma unroll
            for (int mi = 0; mi < 2; ++mi) {
                const int q = w * 32 + mi * 16 + c;
                pf[mi] = *(const fragAB*)(Psb + SWZ(q * 256 + kk * 64 + g * 16, q));
            }
#pragma unroll
            for (int ni = 0; ni < 4; ++ni) {
                const int dd = ni * 16 + c;
                vf[ni] = *(const fragAB*)(Vsb + SWZ(dd * 256 + kk * 64 + g * 16, dd));
            }
#pragma unroll
            for (int mi = 0; mi < 2; ++mi)
#pragma unroll
                for (int ni = 0; ni < 4; ++ni)
                    o[mi][ni] = MFMA(pf[mi], vf[ni], o[mi][ni]);
        }
    }

#pragma unroll
    for (int mi = 0; mi < 2; ++mi)
#pragma unroll
        for (int ni = 0; ni < 4; ++ni) {
            const int dd = ni * 16 + c;
#pragma unroll
            for (int j = 0; j < 4; ++j) {
                const int q = qbase + w * 32 + mi * 16 + g * 4 + j;
                AO[(size_t)(b * 2048 + q) * 1024 + h * 64 + dd] = f2bf(o[mi][ni][j]);
            }
        }
}

// ---------- launcher ----------
extern "C" void kernel_launch(void* const* d_in, const int* in_sizes, int n_in,
                              void* d_out, int out_size, void* d_ws, size_t ws_size,
                              hipStream_t stream) {
    (void)in_sizes; (void)n_in; (void)out_size; (void)ws_size;
    const float* x  = (const float*)d_in[0];
    const float* Wq = (const float*)d_in[1];
    const float* bq = (const float*)d_in[2];
    const float* Wk = (const float*)d_in[3];
    const float* bk = (const float*)d_in[4];
    const float* Wv = (const float*)d_in[5];
    const float* bv = (const float*)d_in[6];
    const float* Wo = (const float*)d_in[7];
    const float* bo = (const float*)d_in[8];

    char* ws = (char*)d_ws;                       // 48MB used
    unsigned short* xb  = (unsigned short*)(ws);                    // 8MB
    unsigned short* Wqb = (unsigned short*)(ws + (8u  << 20));      // 2MB
    unsigned short* Wkb = (unsigned short*)(ws + (10u << 20));
    unsigned short* Wvb = (unsigned short*)(ws + (12u << 20));
    unsigned short* Wob = (unsigned short*)(ws + (14u << 20));
    unsigned short* Qb  = (unsigned short*)(ws + (16u << 20));      // 8MB
    unsigned short* Kb  = (unsigned short*)(ws + (24u << 20));      // 8MB
    unsigned short* Vtb = (unsigned short*)(ws + (32u << 20));      // 8MB, [b][n][s]
    unsigned short* AO  = (unsigned short*)(ws + (40u << 20));      // 8MB

    cvt_bf16<<<4096, 256, 0, stream>>>(x,  xb,  4194304);
    cvt_bf16<<<1024, 256, 0, stream>>>(Wq, Wqb, 1048576);
    cvt_bf16<<<1024, 256, 0, stream>>>(Wk, Wkb, 1048576);
    cvt_bf16<<<1024, 256, 0, stream>>>(Wv, Wvb, 1048576);
    cvt_bf16<<<1024, 256, 0, stream>>>(Wo, Wob, 1048576);

    dim3 gg(8, 32);
    gemm_bt<<<gg, 256, 0, stream>>>(xb, Wqb, bq, Qb,  0);
    gemm_bt<<<gg, 256, 0, stream>>>(xb, Wkb, bk, Kb,  0);
    gemm_bt<<<gg, 256, 0, stream>>>(xb, Wvb, bv, Vtb, 1);

    attn_kernel<<<dim3(16, 16, 2), 256, 0, stream>>>(Qb, Kb, Vtb, AO);

    gemm_bt<<<gg, 256, 0, stream>>>(AO, Wob, bo, d_out, 2);
}

// Round 2
// 125.039 us; speedup vs baseline: 1.3984x; 1.3984x over previous
//
#include <hip/hip_runtime.h>
#include <stdint.h>

// ---------- types ----------
typedef __attribute__((ext_vector_type(8))) __bf16 fragAB;  // 8 bf16 = 4 VGPR
typedef __attribute__((ext_vector_type(4))) float f32x4;

__device__ __forceinline__ unsigned short f2bf(float f) {
    union { float f; unsigned int u; } v; v.f = f;
    unsigned int u = v.u + 0x7fffu + ((v.u >> 16) & 1u);   // RNE
    return (unsigned short)(u >> 16);
}

__device__ __forceinline__ f32x4 MFMA(fragAB a, fragAB b, f32x4 c) {
    return __builtin_amdgcn_mfma_f32_16x16x32_bf16(a, b, c, 0, 0, 0);
}

// async global->LDS, 16B per lane; LDS dest = wave-uniform base + lane*16
__device__ __forceinline__ void gl16(const void* g, void* l) {
    __builtin_amdgcn_global_load_lds((const __attribute__((address_space(1))) void*)g,
                                     (__attribute__((address_space(3))) void*)l, 16, 0, 0);
}

__device__ __forceinline__ float fsin_rev(float rev) {   // sin(2*pi*rev)
    float r; asm("v_sin_f32 %0, %1" : "=v"(r) : "v"(rev)); return r;
}
__device__ __forceinline__ unsigned int cvtpk(float lo, float hi) {  // 2xbf16 RNE
    unsigned int r; asm("v_cvt_pk_bf16_f32 %0, %1, %2" : "=v"(r) : "v"(lo), "v"(hi)); return r;
}

// ---------- fused fp32 -> bf16 convert (x + 4 weights in one launch) ----------
__global__ __launch_bounds__(256) void cvt_all(
    const float* __restrict__ x,  const float* __restrict__ wq, const float* __restrict__ wk,
    const float* __restrict__ wv, const float* __restrict__ wo,
    unsigned short* __restrict__ xb,  unsigned short* __restrict__ wqb, unsigned short* __restrict__ wkb,
    unsigned short* __restrict__ wvb, unsigned short* __restrict__ wob)
{
    const int bid = blockIdx.x;
    const float* s; unsigned short* d; int off;
    if (bid < 4096)      { s = x;  d = xb;  off = bid; }
    else if (bid < 5120) { s = wq; d = wqb; off = bid - 4096; }
    else if (bid < 6144) { s = wk; d = wkb; off = bid - 5120; }
    else if (bid < 7168) { s = wv; d = wvb; off = bid - 6144; }
    else                 { s = wo; d = wob; off = bid - 7168; }
    const int i = (off * 256 + threadIdx.x) * 4;
    float4 f = *(const float4*)(s + i);
    ushort4 o;
    o.x = f2bf(f.x); o.y = f2bf(f.y); o.z = f2bf(f.z); o.w = f2bf(f.w);
    *(ushort4*)(d + i) = o;
}

// ---------- GEMM (m97 structure): C(4096x1024) = A * W^T + bias ----------
// grid (8 n-tiles, 32 m-tiles, z selects weight set). 128x128 tile, BK=64,
// global_load_lds width-16 staging into linear LDS [128][64].
// mode 0: bf16 row-major; mode 1: bf16 transposed Vt[b][n][s]; mode 2: fp32
__global__ __launch_bounds__(256, 2)
void gemm_k(const unsigned short* __restrict__ A,
            const unsigned short* __restrict__ W0, const unsigned short* __restrict__ W1,
            const unsigned short* __restrict__ W2,
            const float* __restrict__ b0, const float* __restrict__ b1, const float* __restrict__ b2,
            void* o0, void* o1, void* o2, int md0, int md1, int md2)
{
    __shared__ unsigned short As[8192];   // [128][64] linear, 16KB
    __shared__ unsigned short Ws[8192];

    const int z = blockIdx.z;
    const unsigned short* W = z == 0 ? W0 : (z == 1 ? W1 : W2);
    const float* bias        = z == 0 ? b0 : (z == 1 ? b1 : b2);
    void* out                = z == 0 ? o0 : (z == 1 ? o1 : o2);
    const int mode           = z == 0 ? md0 : (z == 1 ? md1 : md2);

    const int t = threadIdx.x;
    const int lane = t & 63;
    const int g = lane >> 4;
    const int c = lane & 15;
    const int w = t >> 6;
    const int wm = (w >> 1) * 64;
    const int wn = (w & 1) * 64;
    const int m0 = blockIdx.y * 128;
    const int n0 = blockIdx.x * 128;

    const int srow = lane >> 3;          // row within 8-row chunk
    const int scol = (lane & 7) * 8;     // elem col within 64

    const f32x4 zz = {0.f, 0.f, 0.f, 0.f};
    f32x4 acc[4][4];
#pragma unroll
    for (int mi = 0; mi < 4; ++mi)
#pragma unroll
        for (int ni = 0; ni < 4; ++ni) acc[mi][ni] = zz;

    for (int kt = 0; kt < 16; ++kt) {
        const int k0 = kt * 64;
#pragma unroll
        for (int r = 0; r < 4; ++r) {
            gl16(A + (size_t)(m0 + 32 * w + 8 * r + srow) * 1024 + k0 + scol,
                 (unsigned short*)As + (w * 4 + r) * 512);
            gl16(W + (size_t)(n0 + 32 * w + 8 * r + srow) * 1024 + k0 + scol,
                 (unsigned short*)Ws + (w * 4 + r) * 512);
        }
        __syncthreads();                 // drains vmcnt -> tiles resident
#pragma unroll
        for (int kk = 0; kk < 2; ++kk) {
            fragAB af[4], bfr[4];
#pragma unroll
            for (int mi = 0; mi < 4; ++mi)
                af[mi] = *(const fragAB*)((char*)As + (wm + mi * 16 + c) * 128 + kk * 64 + g * 16);
#pragma unroll
            for (int ni = 0; ni < 4; ++ni)
                bfr[ni] = *(const fragAB*)((char*)Ws + (wn + ni * 16 + c) * 128 + kk * 64 + g * 16);
#pragma unroll
            for (int mi = 0; mi < 4; ++mi)
#pragma unroll
                for (int ni = 0; ni < 4; ++ni)
                    acc[mi][ni] = MFMA(af[mi], bfr[ni], acc[mi][ni]);
        }
        __syncthreads();                 // reads done before next stage
    }

    float bv[4];
#pragma unroll
    for (int ni = 0; ni < 4; ++ni) bv[ni] = bias[n0 + wn + ni * 16 + c];

    if (mode == 0) {
        unsigned short* C = (unsigned short*)out;
#pragma unroll
        for (int mi = 0; mi < 4; ++mi)
#pragma unroll
            for (int ni = 0; ni < 4; ++ni)
#pragma unroll
                for (int j = 0; j < 4; ++j) {
                    const int grow = m0 + wm + mi * 16 + g * 4 + j;
                    const int gcol = n0 + wn + ni * 16 + c;
                    C[(size_t)grow * 1024 + gcol] = f2bf(acc[mi][ni][j] + bv[ni]);
                }
    } else if (mode == 1) {
        unsigned short* Vt = (unsigned short*)out;   // Vt[b][n][s]
#pragma unroll
        for (int mi = 0; mi < 4; ++mi)
#pragma unroll
            for (int ni = 0; ni < 4; ++ni) {
                const int gcol = n0 + wn + ni * 16 + c;
                const int mrow = m0 + wm + mi * 16 + g * 4;
                const int bb = mrow >> 11;
                const int s = mrow & 2047;
                ushort4 pk;
                pk.x = f2bf(acc[mi][ni][0] + bv[ni]);
                pk.y = f2bf(acc[mi][ni][1] + bv[ni]);
                pk.z = f2bf(acc[mi][ni][2] + bv[ni]);
                pk.w = f2bf(acc[mi][ni][3] + bv[ni]);
                *(ushort4*)(Vt + ((size_t)bb * 1024 + gcol) * 2048 + s) = pk;
            }
    } else {
        float* C = (float*)out;
#pragma unroll
        for (int mi = 0; mi < 4; ++mi)
#pragma unroll
            for (int ni = 0; ni < 4; ++ni)
#pragma unroll
                for (int j = 0; j < 4; ++j) {
                    const int grow = m0 + wm + mi * 16 + g * 4 + j;
                    const int gcol = n0 + wn + ni * 16 + c;
                    C[(size_t)grow * 1024 + gcol] = acc[mi][ni][j] + bv[ni];
                }
    }
}

// ---------- fused sine attention ----------
// KVBLK=64, K/V double-buffered via async global_load_lds (pre-swizzled source,
// linear dest, swizzled read). Q hoisted to regs. 2 barriers/iter; only the
// loop-top __syncthreads drains vmcnt -> one full iter of latency hiding.
#define SWZ(byteoff, row) ((byteoff) ^ (((row) & 7) << 4))
#define SIN_SC 0.5968310366f   // 3.75 / (2*pi)

__global__ __launch_bounds__(256, 3)
void attn_kernel(const unsigned short* __restrict__ Qg,
                 const unsigned short* __restrict__ Kg,
                 const unsigned short* __restrict__ Vg,   // Vt[b][n][s]
                 unsigned short* __restrict__ AO)
{
    __shared__ unsigned short Ks[2 * 4096];   // 2 x [64 k][64 d], 16KB
    __shared__ unsigned short Vs[2 * 4096];   // 2 x [64 d][64 k], 16KB
    __shared__ unsigned short Ps[8192];       // [128 q][64 k],    16KB

    const int t = threadIdx.x;
    const int lane = t & 63;
    const int g = lane >> 4;
    const int c = lane & 15;
    const int w = t >> 6;
    const int qb = blockIdx.x, h = blockIdx.y, b = blockIdx.z;
    const int qbase = qb * 128;

    char* const Ksb = (char*)Ks;
    char* const Vsb = (char*)Vs;
    char* const Psb = (char*)Ps;

    // staging geometry: chunk = 8 rows x 64 cols; source col pre-swizzled (rule #21)
    const int rowoff = lane >> 3;
    const int col8 = (lane & 7) ^ rowoff;
    const int ch0 = 2 * w, ch1 = 2 * w + 1;
    const unsigned short* Kg0 = Kg + (size_t)(b * 2048 + 8 * ch0 + rowoff) * 1024 + h * 64 + col8 * 8;
    const unsigned short* Kg1 = Kg + (size_t)(b * 2048 + 8 * ch1 + rowoff) * 1024 + h * 64 + col8 * 8;
    const unsigned short* Vg0 = Vg + ((size_t)b * 1024 + h * 64 + 8 * ch0 + rowoff) * 2048 + col8 * 8;
    const unsigned short* Vg1 = Vg + ((size_t)b * 1024 + h * 64 + 8 * ch1 + rowoff) * 2048 + col8 * 8;

    // prologue: stage kb=0 into buffer 0
    gl16(Kg0, (unsigned short*)Ks + ch0 * 512);
    gl16(Kg1, (unsigned short*)Ks + ch1 * 512);
    gl16(Vg0, (unsigned short*)Vs + ch0 * 512);
    gl16(Vg1, (unsigned short*)Vs + ch1 * 512);

    // Q fragments in registers (loop-invariant): B-operand lane holds Q[16qi+c][kk*32+g*8..+8]
    fragAB qreg[2][8];
#pragma unroll
    for (int kk = 0; kk < 2; ++kk)
#pragma unroll
        for (int qi = 0; qi < 8; ++qi)
            qreg[kk][qi] = *(const fragAB*)(Qg + (size_t)(b * 2048 + qbase + qi * 16 + c) * 1024
                                            + h * 64 + kk * 32 + g * 8);

    const f32x4 z = {0.f, 0.f, 0.f, 0.f};
    f32x4 o[2][4];
#pragma unroll
    for (int mi = 0; mi < 2; ++mi)
#pragma unroll
        for (int ni = 0; ni < 4; ++ni) o[mi][ni] = z;

    const int krow = 16 * w + c;
    const int pkbyte = (16 * w + g * 4) * 2;

    for (int kb = 0; kb < 32; ++kb) {
        const int cur = kb & 1;
        char* const kc = Ksb + cur * 8192;
        char* const vc = Vsb + cur * 8192;

        __syncthreads();   // drains vmcnt: buf[cur] staged; prev Ps/V reads done

        if (kb < 31) {     // prefetch next K/V chunk into buf[cur^1]
            const int nxt = cur ^ 1;
            unsigned short* kl = (unsigned short*)Ks + nxt * 4096;
            unsigned short* vl = (unsigned short*)Vs + nxt * 4096;
            const size_t ko = (size_t)(kb + 1) * 65536;   // 64 rows * 1024
            const int vo = (kb + 1) * 64;
            gl16(Kg0 + ko, kl + ch0 * 512);
            gl16(Kg1 + ko, kl + ch1 * 512);
            gl16(Vg0 + vo, vl + ch0 * 512);
            gl16(Vg1 + vo, vl + ch1 * 512);
        }

        // St = K * Q^T : wave w owns k rows [16w,16w+16), all 128 q
        fragAB kf0 = *(const fragAB*)(kc + SWZ(krow * 128 + g * 16, krow));
        fragAB kf1 = *(const fragAB*)(kc + SWZ(krow * 128 + 64 + g * 16, krow));
        f32x4 st[8];
#pragma unroll
        for (int qi = 0; qi < 8; ++qi) st[qi] = z;
#pragma unroll
        for (int qi = 0; qi < 8; ++qi) {
            st[qi] = MFMA(kf0, qreg[0][qi], st[qi]);
            st[qi] = MFMA(kf1, qreg[1][qi], st[qi]);
        }

        // P = sin(3.75*St) -> Ps[q][k] (regs j are k-consecutive -> 8B store)
#pragma unroll
        for (int qi = 0; qi < 8; ++qi) {
            const int q = qi * 16 + c;
            float s0 = fsin_rev(st[qi][0] * SIN_SC);
            float s1 = fsin_rev(st[qi][1] * SIN_SC);
            float s2 = fsin_rev(st[qi][2] * SIN_SC);
            float s3 = fsin_rev(st[qi][3] * SIN_SC);
            uint2 pk;
            pk.x = cvtpk(s0, s1);
            pk.y = cvtpk(s2, s3);
            *(uint2*)(Psb + SWZ(q * 128 + pkbyte, q)) = pk;
        }

        asm volatile("s_waitcnt lgkmcnt(0)" ::: "memory");  // Ps visible
        __builtin_amdgcn_s_barrier();                       // no vmcnt drain!

        // O += P * V : wave w owns q rows [32w,32w+32), d 0..63
#pragma unroll
        for (int kk = 0; kk < 2; ++kk) {
            fragAB pf[2], vf[4];
#pragma unroll
            for (int mi = 0; mi < 2; ++mi) {
                const int q = 32 * w + mi * 16 + c;
                pf[mi] = *(const fragAB*)(Psb + SWZ(q * 128 + kk * 64 + g * 16, q));
            }
#pragma unroll
            for (int ni = 0; ni < 4; ++ni) {
                const int dd = ni * 16 + c;
                vf[ni] = *(const fragAB*)(vc + SWZ(dd * 128 + kk * 64 + g * 16, dd));
            }
#pragma unroll
            for (int mi = 0; mi < 2; ++mi)
#pragma unroll
                for (int ni = 0; ni < 4; ++ni)
                    o[mi][ni] = MFMA(pf[mi], vf[ni], o[mi][ni]);
        }
    }

#pragma unroll
    for (int mi = 0; mi < 2; ++mi)
#pragma unroll
        for (int ni = 0; ni < 4; ++ni) {
            const int dd = ni * 16 + c;
#pragma unroll
            for (int j = 0; j < 4; ++j) {
                const int q = qbase + 32 * w + mi * 16 + g * 4 + j;
                AO[(size_t)(b * 2048 + q) * 1024 + h * 64 + dd] = f2bf(o[mi][ni][j]);
            }
        }
}

// ---------- launcher ----------
extern "C" void kernel_launch(void* const* d_in, const int* in_sizes, int n_in,
                              void* d_out, int out_size, void* d_ws, size_t ws_size,
                              hipStream_t stream) {
    (void)in_sizes; (void)n_in; (void)out_size; (void)ws_size;
    const float* x  = (const float*)d_in[0];
    const float* Wq = (const float*)d_in[1];
    const float* bq = (const float*)d_in[2];
    const float* Wk = (const float*)d_in[3];
    const float* bk = (const float*)d_in[4];
    const float* Wv = (const float*)d_in[5];
    const float* bv = (const float*)d_in[6];
    const float* Wo = (const float*)d_in[7];
    const float* bo = (const float*)d_in[8];

    char* ws = (char*)d_ws;
    unsigned short* xb  = (unsigned short*)(ws);                    // 8MB
    unsigned short* Wqb = (unsigned short*)(ws + (8u  << 20));      // 2MB each
    unsigned short* Wkb = (unsigned short*)(ws + (10u << 20));
    unsigned short* Wvb = (unsigned short*)(ws + (12u << 20));
    unsigned short* Wob = (unsigned short*)(ws + (14u << 20));
    unsigned short* Qb  = (unsigned short*)(ws + (16u << 20));      // 8MB
    unsigned short* Kb  = (unsigned short*)(ws + (24u << 20));      // 8MB
    unsigned short* Vtb = (unsigned short*)(ws + (32u << 20));      // 8MB, [b][n][s]
    unsigned short* AO  = (unsigned short*)(ws + (40u << 20));      // 8MB

    cvt_all<<<8192, 256, 0, stream>>>(x, Wq, Wk, Wv, Wo, xb, Wqb, Wkb, Wvb, Wob);

    gemm_k<<<dim3(8, 32, 3), 256, 0, stream>>>(xb, Wqb, Wkb, Wvb, bq, bk, bv,
                                               Qb, Kb, Vtb, 0, 0, 1);

    attn_kernel<<<dim3(16, 16, 2), 256, 0, stream>>>(Qb, Kb, Vtb, AO);

    gemm_k<<<dim3(8, 32, 1), 256, 0, stream>>>(AO, Wob, Wob, Wob, bo, bo, bo,
                                               d_out, d_out, d_out, 2, 2, 2);
}